// Round 1
// baseline (1911.256 us; speedup 1.0000x reference)
//
#include <hip/hip_runtime.h>
#include <math.h>

#define NN 100000
#define NE 3200000
#define INF 384
#define HID 64

// ---------------- degree / norm ----------------

__global__ void zero_kernel(float* __restrict__ p, int n) {
    int i = blockIdx.x * blockDim.x + threadIdx.x;
    if (i < n) p[i] = 0.f;
}

__global__ void deg_kernel(const int* __restrict__ col, const float* __restrict__ ew,
                           float* __restrict__ deg) {
    int e = blockIdx.x * blockDim.x + threadIdx.x;
    if (e < NE) atomicAdd(&deg[col[e]], ew[e]);
}

__global__ void dis_kernel(float* __restrict__ deg) {
    int i = blockIdx.x * blockDim.x + threadIdx.x;
    if (i < NN) {
        float d = deg[i] + 1.0f;  // self-loop weight 1
        deg[i] = d > 0.f ? rsqrtf(d) : 0.f;
    }
}

// ---------------- GEMM: out[N x 64] = act(A[N x K]) @ W[K x 64] ----------------
// 64-node x 64-col tile per block, 256 threads, 4x4 register blocking.

template <int K, bool LEAKY>
__global__ __launch_bounds__(256) void gemm_kernel(const float* __restrict__ A,
                                                   const float* __restrict__ W,
                                                   float* __restrict__ out) {
    __shared__ float Xs[64][68];  // [k][node], padded
    __shared__ float Ws[64][64];  // [k][j]
    const int nb = blockIdx.x * 64;
    const int jt = threadIdx.x & 15;   // j-tile: cols jt*4 .. jt*4+3
    const int nt = threadIdx.x >> 4;   // n-tile: nodes nt*4 .. nt*4+3

    float acc[4][4];
#pragma unroll
    for (int a = 0; a < 4; a++)
#pragma unroll
        for (int b = 0; b < 4; b++) acc[a][b] = 0.f;

    for (int k0 = 0; k0 < K; k0 += 64) {
        // stage A tile (transposed into Xs[k][node])
#pragma unroll
        for (int l = 0; l < 4; l++) {
            int idx = threadIdx.x + l * 256;  // 0..1023 float4 slots
            int r = idx >> 4;                 // node row 0..63
            int c = (idx & 15) * 4;           // k col 0..60
            int gr = nb + r;
            float4 v = make_float4(0.f, 0.f, 0.f, 0.f);
            if (gr < NN) v = *(const float4*)&A[(size_t)gr * K + k0 + c];
            if (LEAKY) {
                v.x = v.x > 0.f ? v.x : 0.01f * v.x;
                v.y = v.y > 0.f ? v.y : 0.01f * v.y;
                v.z = v.z > 0.f ? v.z : 0.01f * v.z;
                v.w = v.w > 0.f ? v.w : 0.01f * v.w;
            }
            Xs[c][r] = v.x; Xs[c + 1][r] = v.y; Xs[c + 2][r] = v.z; Xs[c + 3][r] = v.w;
        }
        // stage W tile
#pragma unroll
        for (int l = 0; l < 4; l++) {
            int idx = threadIdx.x + l * 256;
            int r = idx >> 4;
            int c = (idx & 15) * 4;
            *(float4*)&Ws[r][c] = *(const float4*)&W[(size_t)(k0 + r) * HID + c];
        }
        __syncthreads();

#pragma unroll 8
        for (int k = 0; k < 64; k++) {
            float4 xv = *(const float4*)&Xs[k][nt * 4];
            float4 wv = *(const float4*)&Ws[k][jt * 4];
            float xa[4] = {xv.x, xv.y, xv.z, xv.w};
            float wa[4] = {wv.x, wv.y, wv.z, wv.w};
#pragma unroll
            for (int a = 0; a < 4; a++)
#pragma unroll
                for (int b = 0; b < 4; b++) acc[a][b] = fmaf(xa[a], wa[b], acc[a][b]);
        }
        __syncthreads();
    }

#pragma unroll
    for (int a = 0; a < 4; a++) {
        int node = nb + nt * 4 + a;
        if (node < NN) {
            float4 o = make_float4(acc[a][0], acc[a][1], acc[a][2], acc[a][3]);
            *(float4*)&out[(size_t)node * HID + jt * 4] = o;
        }
    }
}

// ---------------- conv aggregation ----------------
// init: out[n][j] = bias[j] + dis[n]^2 * h[n][j]   (self-loop term, norm=dis*1*dis)

__global__ void conv_init_kernel(const float* __restrict__ dis, const float* __restrict__ h,
                                 const float* __restrict__ bias, float* __restrict__ out) {
    int i = blockIdx.x * blockDim.x + threadIdx.x;
    if (i < NN * HID) {
        int n = i >> 6;
        int j = i & 63;
        float d = dis[n];
        out[i] = bias[j] + d * d * h[i];
    }
}

// edges: out[col] += (dis[row]*w*dis[col]) * h[row]   — wave per edge, lane = feature
__global__ __launch_bounds__(256) void scatter_kernel(const int* __restrict__ row,
                                                      const int* __restrict__ col,
                                                      const float* __restrict__ ew,
                                                      const float* __restrict__ dis,
                                                      const float* __restrict__ h,
                                                      float* __restrict__ out) {
    int lane = threadIdx.x & 63;
    int wid = blockIdx.x * (blockDim.x >> 6) + (threadIdx.x >> 6);
    int stride = gridDim.x * (blockDim.x >> 6);
    for (int e = wid; e < NE; e += stride) {
        int r = row[e];
        int c = col[e];
        float nrm = dis[r] * ew[e] * dis[c];
        float v = nrm * h[(size_t)r * HID + lane];
        atomicAdd(&out[(size_t)c * HID + lane], v);
    }
}

// ---------------- MLP head + softmax (wave per node) ----------------

__global__ __launch_bounds__(256) void mlp_kernel(const float* __restrict__ agg,
                                                  const float* __restrict__ Wm1,
                                                  const float* __restrict__ bm1,
                                                  const float* __restrict__ Wm2,
                                                  const float* __restrict__ bm2,
                                                  float* __restrict__ out) {
    __shared__ float W1s[64 * 64];
    __shared__ float W2s[128];
    for (int idx = threadIdx.x * 4; idx < 64 * 64; idx += 256 * 4)
        *(float4*)&W1s[idx] = *(const float4*)&Wm1[idx];
    if (threadIdx.x < 128) W2s[threadIdx.x] = Wm2[threadIdx.x];
    __syncthreads();

    int lane = threadIdx.x & 63;
    int wid = threadIdx.x >> 6;
    int gw = blockIdx.x * 4 + wid;
    int nw = gridDim.x * 4;
    float b1v = bm1[lane];
    float b20 = bm2[0], b21 = bm2[1];
    float w20 = W2s[lane * 2], w21 = W2s[lane * 2 + 1];

    for (int n = gw; n < NN; n += nw) {
        float hv = agg[(size_t)n * HID + lane];
        float acc = b1v;
#pragma unroll
        for (int k = 0; k < 64; k++) acc = fmaf(__shfl(hv, k), W1s[k * 64 + lane], acc);
        float u = acc > 0.f ? acc : (expf(acc) - 1.f);  // ELU
        float p0 = u * w20;
        float p1 = u * w21;
#pragma unroll
        for (int off = 32; off > 0; off >>= 1) {
            p0 += __shfl_xor(p0, off);
            p1 += __shfl_xor(p1, off);
        }
        if (lane == 0) {
            float l0 = p0 + b20, l1 = p1 + b21;
            float m = fmaxf(l0, l1);
            float e0 = expf(l0 - m), e1 = expf(l1 - m);
            float inv = 1.f / (e0 + e1);
            out[(size_t)n * 2] = e0 * inv;
            out[(size_t)n * 2 + 1] = e1 * inv;
        }
    }
}

// ---------------- launch ----------------

extern "C" void kernel_launch(void* const* d_in, const int* in_sizes, int n_in,
                              void* d_out, int out_size, void* d_ws, size_t ws_size,
                              hipStream_t stream) {
    const float* X   = (const float*)d_in[0];
    const int*   ei  = (const int*)d_in[1];
    const float* ew  = (const float*)d_in[2];
    const float* W1  = (const float*)d_in[3];
    const float* b1  = (const float*)d_in[4];
    const float* W2  = (const float*)d_in[5];
    const float* b2  = (const float*)d_in[6];
    const float* Wm1 = (const float*)d_in[7];
    const float* bm1 = (const float*)d_in[8];
    const float* Wm2 = (const float*)d_in[9];
    const float* bm2 = (const float*)d_in[10];
    const int* row = ei;
    const int* col = ei + NE;
    float* out = (float*)d_out;

    char* ws = (char*)d_ws;
    float* dis = (float*)ws;                                   // NN floats (0.4 MB)
    float* h1  = (float*)(ws + (size_t)1 * 1024 * 1024);       // NN*64 (25.6 MB)
    float* h2  = (float*)(ws + (size_t)28 * 1024 * 1024);      // NN*64 (25.6 MB)

    // gcn_norm
    zero_kernel<<<(NN + 255) / 256, 256, 0, stream>>>(dis, NN);
    deg_kernel<<<(NE + 255) / 256, 256, 0, stream>>>(col, ew, dis);
    dis_kernel<<<(NN + 255) / 256, 256, 0, stream>>>(dis);

    // conv1: h1 = X @ W1 ; h2 = b1 + selfloop + scatter
    gemm_kernel<INF, false><<<(NN + 63) / 64, 256, 0, stream>>>(X, W1, h1);
    conv_init_kernel<<<(NN * HID + 255) / 256, 256, 0, stream>>>(dis, h1, b1, h2);
    scatter_kernel<<<8192, 256, 0, stream>>>(row, col, ew, dis, h1, h2);

    // conv2: h1 = leaky(h2) @ W2 ; h2 = b2 + selfloop + scatter
    gemm_kernel<HID, true><<<(NN + 63) / 64, 256, 0, stream>>>(h2, W2, h1);
    conv_init_kernel<<<(NN * HID + 255) / 256, 256, 0, stream>>>(dis, h1, b2, h2);
    scatter_kernel<<<8192, 256, 0, stream>>>(row, col, ew, dis, h1, h2);

    // MLP head + softmax
    mlp_kernel<<<2048, 256, 0, stream>>>(h2, Wm1, bm1, Wm2, bm2, out);
}

// Round 2
// 1127.560 us; speedup vs baseline: 1.6950x; 1.6950x over previous
//
#include <hip/hip_runtime.h>
#include <math.h>

#define NN 100000
#define NE 3200000
#define INF 384
#define HID 64
#define SCAN_BLK 98   // ceil(NN/1024)

// ---------------- zero deg + counts ----------------

__global__ void zero_kernel(float* __restrict__ deg, int* __restrict__ offs) {
    int i = blockIdx.x * blockDim.x + threadIdx.x;
    if (i <= NN) offs[i] = 0;
    if (i < NN) deg[i] = 0.f;
}

// per-edge: histogram of dest + weighted degree (fused, reads col once)
__global__ void hist_deg_kernel(const int* __restrict__ col, const float* __restrict__ ew,
                                int* __restrict__ offs, float* __restrict__ deg) {
    int e = blockIdx.x * blockDim.x + threadIdx.x;
    if (e < NE) {
        int c = col[e];
        atomicAdd(&offs[c], 1);
        atomicAdd(&deg[c], ew[e]);
    }
}

__global__ void dis_kernel(float* __restrict__ deg) {
    int i = blockIdx.x * blockDim.x + threadIdx.x;
    if (i < NN) {
        float d = deg[i] + 1.0f;  // self-loop weight 1; always > 0
        deg[i] = rsqrtf(d);
    }
}

// ---------------- exclusive scan over counts (3 kernels) ----------------

__global__ __launch_bounds__(256) void scan1_kernel(int* __restrict__ offs, int* __restrict__ bsum) {
    __shared__ int sd[256];
    int base = blockIdx.x * 1024 + threadIdx.x * 4;
    int v[4];
    int t = 0;
#pragma unroll
    for (int i = 0; i < 4; i++) {
        int idx = base + i;
        v[i] = (idx < NN) ? offs[idx] : 0;
        t += v[i];
    }
    sd[threadIdx.x] = t;
    __syncthreads();
    for (int off = 1; off < 256; off <<= 1) {
        int x = (threadIdx.x >= off) ? sd[threadIdx.x - off] : 0;
        __syncthreads();
        sd[threadIdx.x] += x;
        __syncthreads();
    }
    int run = sd[threadIdx.x] - t;  // exclusive
#pragma unroll
    for (int i = 0; i < 4; i++) {
        int idx = base + i;
        if (idx < NN) offs[idx] = run;
        run += v[i];
    }
    if (threadIdx.x == 255) bsum[blockIdx.x] = sd[255];
}

__global__ void scan2_kernel(int* __restrict__ bsum) {
    __shared__ int sd[128];
    int t = (threadIdx.x < SCAN_BLK) ? bsum[threadIdx.x] : 0;
    sd[threadIdx.x] = t;
    __syncthreads();
    for (int off = 1; off < 128; off <<= 1) {
        int x = (threadIdx.x >= off) ? sd[threadIdx.x - off] : 0;
        __syncthreads();
        sd[threadIdx.x] += x;
        __syncthreads();
    }
    if (threadIdx.x < SCAN_BLK) bsum[threadIdx.x] = sd[threadIdx.x] - t;  // exclusive
}

__global__ void scan3_kernel(int* __restrict__ offs, const int* __restrict__ bsum,
                             int* __restrict__ cursor) {
    int i = blockIdx.x * blockDim.x + threadIdx.x;
    if (i < NN) {
        int v = offs[i] + bsum[i >> 10];
        offs[i] = v;
        cursor[i] = v;
    }
    if (i == 0) offs[NN] = NE;
}

// ---------------- scatter edges into CSR slots, norm precomputed ----------------

__global__ void build_kernel(const int* __restrict__ row, const int* __restrict__ col,
                             const float* __restrict__ ew, const float* __restrict__ dis,
                             int* __restrict__ cursor, int* __restrict__ srow,
                             float* __restrict__ snorm) {
    int e = blockIdx.x * blockDim.x + threadIdx.x;
    if (e < NE) {
        int r = row[e];
        int c = col[e];
        int pos = atomicAdd(&cursor[c], 1);
        srow[pos] = r;
        snorm[pos] = dis[r] * ew[e] * dis[c];
    }
}

// ---------------- GEMM: out[N x 64] = act(A[N x K]) @ W[K x 64] ----------------

template <int K, bool LEAKY>
__global__ __launch_bounds__(256) void gemm_kernel(const float* __restrict__ A,
                                                   const float* __restrict__ W,
                                                   float* __restrict__ out) {
    __shared__ float Xs[64][68];  // [k][node], padded
    __shared__ float Ws[64][64];  // [k][j]
    const int nb = blockIdx.x * 64;
    const int jt = threadIdx.x & 15;
    const int nt = threadIdx.x >> 4;

    float acc[4][4];
#pragma unroll
    for (int a = 0; a < 4; a++)
#pragma unroll
        for (int b = 0; b < 4; b++) acc[a][b] = 0.f;

    for (int k0 = 0; k0 < K; k0 += 64) {
#pragma unroll
        for (int l = 0; l < 4; l++) {
            int idx = threadIdx.x + l * 256;
            int r = idx >> 4;
            int c = (idx & 15) * 4;
            int gr = nb + r;
            float4 v = make_float4(0.f, 0.f, 0.f, 0.f);
            if (gr < NN) v = *(const float4*)&A[(size_t)gr * K + k0 + c];
            if (LEAKY) {
                v.x = v.x > 0.f ? v.x : 0.01f * v.x;
                v.y = v.y > 0.f ? v.y : 0.01f * v.y;
                v.z = v.z > 0.f ? v.z : 0.01f * v.z;
                v.w = v.w > 0.f ? v.w : 0.01f * v.w;
            }
            Xs[c][r] = v.x; Xs[c + 1][r] = v.y; Xs[c + 2][r] = v.z; Xs[c + 3][r] = v.w;
        }
#pragma unroll
        for (int l = 0; l < 4; l++) {
            int idx = threadIdx.x + l * 256;
            int r = idx >> 4;
            int c = (idx & 15) * 4;
            *(float4*)&Ws[r][c] = *(const float4*)&W[(size_t)(k0 + r) * HID + c];
        }
        __syncthreads();

#pragma unroll 8
        for (int k = 0; k < 64; k++) {
            float4 xv = *(const float4*)&Xs[k][nt * 4];
            float4 wv = *(const float4*)&Ws[k][jt * 4];
            float xa[4] = {xv.x, xv.y, xv.z, xv.w};
            float wa[4] = {wv.x, wv.y, wv.z, wv.w};
#pragma unroll
            for (int a = 0; a < 4; a++)
#pragma unroll
                for (int b = 0; b < 4; b++) acc[a][b] = fmaf(xa[a], wa[b], acc[a][b]);
        }
        __syncthreads();
    }

#pragma unroll
    for (int a = 0; a < 4; a++) {
        int node = nb + nt * 4 + a;
        if (node < NN) {
            float4 o = make_float4(acc[a][0], acc[a][1], acc[a][2], acc[a][3]);
            *(float4*)&out[(size_t)node * HID + jt * 4] = o;
        }
    }
}

// ---------------- CSR aggregate: wave per node, lane = feature ----------------
// out[n][lane] = bias[lane] + dis[n]^2 * h[n][lane] + sum_e norm[e]*h[srow[e]][lane]

__global__ __launch_bounds__(256) void aggregate_kernel(const int* __restrict__ offs,
                                                        const int* __restrict__ srow,
                                                        const float* __restrict__ snorm,
                                                        const float* __restrict__ dis,
                                                        const float* __restrict__ h,
                                                        const float* __restrict__ bias,
                                                        float* __restrict__ out) {
    int lane = threadIdx.x & 63;
    int n = blockIdx.x * 4 + (threadIdx.x >> 6);
    if (n >= NN) return;
    float d = dis[n];
    float acc = bias[lane] + d * d * h[(size_t)n * HID + lane];
    int e = offs[n];
    int e2 = offs[n + 1];
    for (; e + 3 < e2; e += 4) {
        int r0 = srow[e], r1 = srow[e + 1], r2 = srow[e + 2], r3 = srow[e + 3];
        float w0 = snorm[e], w1 = snorm[e + 1], w2 = snorm[e + 2], w3 = snorm[e + 3];
        float v0 = h[(size_t)r0 * HID + lane];
        float v1 = h[(size_t)r1 * HID + lane];
        float v2 = h[(size_t)r2 * HID + lane];
        float v3 = h[(size_t)r3 * HID + lane];
        acc = fmaf(w0, v0, acc);
        acc = fmaf(w1, v1, acc);
        acc = fmaf(w2, v2, acc);
        acc = fmaf(w3, v3, acc);
    }
    for (; e < e2; e++) acc = fmaf(snorm[e], h[(size_t)srow[e] * HID + lane], acc);
    out[(size_t)n * HID + lane] = acc;
}

// ---------------- MLP head + softmax (wave per node) ----------------

__global__ __launch_bounds__(256) void mlp_kernel(const float* __restrict__ agg,
                                                  const float* __restrict__ Wm1,
                                                  const float* __restrict__ bm1,
                                                  const float* __restrict__ Wm2,
                                                  const float* __restrict__ bm2,
                                                  float* __restrict__ out) {
    __shared__ float W1s[64 * 64];
    __shared__ float W2s[128];
    for (int idx = threadIdx.x * 4; idx < 64 * 64; idx += 256 * 4)
        *(float4*)&W1s[idx] = *(const float4*)&Wm1[idx];
    if (threadIdx.x < 128) W2s[threadIdx.x] = Wm2[threadIdx.x];
    __syncthreads();

    int lane = threadIdx.x & 63;
    int wid = threadIdx.x >> 6;
    int gw = blockIdx.x * 4 + wid;
    int nw = gridDim.x * 4;
    float b1v = bm1[lane];
    float b20 = bm2[0], b21 = bm2[1];
    float w20 = W2s[lane * 2], w21 = W2s[lane * 2 + 1];

    for (int n = gw; n < NN; n += nw) {
        float hv = agg[(size_t)n * HID + lane];
        float acc = b1v;
#pragma unroll
        for (int k = 0; k < 64; k++) acc = fmaf(__shfl(hv, k), W1s[k * 64 + lane], acc);
        float u = acc > 0.f ? acc : (expf(acc) - 1.f);  // ELU
        float p0 = u * w20;
        float p1 = u * w21;
#pragma unroll
        for (int off = 32; off > 0; off >>= 1) {
            p0 += __shfl_xor(p0, off);
            p1 += __shfl_xor(p1, off);
        }
        if (lane == 0) {
            float l0 = p0 + b20, l1 = p1 + b21;
            float m = fmaxf(l0, l1);
            float e0 = expf(l0 - m), e1 = expf(l1 - m);
            float inv = 1.f / (e0 + e1);
            out[(size_t)n * 2] = e0 * inv;
            out[(size_t)n * 2 + 1] = e1 * inv;
        }
    }
}

// ---------------- launch ----------------

extern "C" void kernel_launch(void* const* d_in, const int* in_sizes, int n_in,
                              void* d_out, int out_size, void* d_ws, size_t ws_size,
                              hipStream_t stream) {
    const float* X   = (const float*)d_in[0];
    const int*   ei  = (const int*)d_in[1];
    const float* ew  = (const float*)d_in[2];
    const float* W1  = (const float*)d_in[3];
    const float* b1  = (const float*)d_in[4];
    const float* W2  = (const float*)d_in[5];
    const float* b2  = (const float*)d_in[6];
    const float* Wm1 = (const float*)d_in[7];
    const float* bm1 = (const float*)d_in[8];
    const float* Wm2 = (const float*)d_in[9];
    const float* bm2 = (const float*)d_in[10];
    const int* row = ei;
    const int* col = ei + NE;
    float* out = (float*)d_out;

    const size_t MB = 1024 * 1024;
    char* ws = (char*)d_ws;
    float* dis    = (float*)(ws + 0 * MB);        // NN floats        (0.4 MB)
    int*   offs   = (int*)  (ws + 1 * MB);        // NN+1 ints        (0.4 MB)
    int*   cursor = (int*)  (ws + 2 * MB);        // NN ints          (0.4 MB)
    int*   bsum   = (int*)  (ws + 3 * MB);        // 128 ints
    int*   srow   = (int*)  (ws + 4 * MB);        // NE ints          (12.8 MB)
    float* snorm  = (float*)(ws + 17 * MB);       // NE floats        (12.8 MB)
    float* h1     = (float*)(ws + 30 * MB);       // NN*64            (25.6 MB)
    float* h2     = (float*)(ws + 56 * MB);       // NN*64            (25.6 MB)

    // ---- norm + CSR build ----
    zero_kernel<<<(NN + 256) / 256, 256, 0, stream>>>(dis, offs);
    hist_deg_kernel<<<(NE + 255) / 256, 256, 0, stream>>>(col, ew, offs, dis);
    dis_kernel<<<(NN + 255) / 256, 256, 0, stream>>>(dis);
    scan1_kernel<<<SCAN_BLK, 256, 0, stream>>>(offs, bsum);
    scan2_kernel<<<1, 128, 0, stream>>>(bsum);
    scan3_kernel<<<(NN + 255) / 256, 256, 0, stream>>>(offs, bsum, cursor);
    build_kernel<<<(NE + 255) / 256, 256, 0, stream>>>(row, col, ew, dis, cursor, srow, snorm);

    // ---- conv1 ----
    gemm_kernel<INF, false><<<(NN + 63) / 64, 256, 0, stream>>>(X, W1, h1);
    aggregate_kernel<<<(NN + 3) / 4, 256, 0, stream>>>(offs, srow, snorm, dis, h1, b1, h2);

    // ---- conv2 ----
    gemm_kernel<HID, true><<<(NN + 63) / 64, 256, 0, stream>>>(h2, W2, h1);
    aggregate_kernel<<<(NN + 3) / 4, 256, 0, stream>>>(offs, srow, snorm, dis, h1, b2, h2);

    // ---- MLP head + softmax ----
    mlp_kernel<<<2048, 256, 0, stream>>>(h2, Wm1, bm1, Wm2, bm2, out);
}

// Round 3
// 875.238 us; speedup vs baseline: 2.1837x; 1.2883x over previous
//
#include <hip/hip_runtime.h>
#include <math.h>

#define NN 100000
#define NE 3200000
#define INF 384
#define HID 64
#define CAP 48
#define OVF_CAP 65536

typedef unsigned long long ulong64;
typedef unsigned int uint32;

// ---------------- init: bucket cursors, extra-degree, overflow count ----------------

__global__ void init_kernel(int* __restrict__ cursor, float* __restrict__ degx,
                            int* __restrict__ ovf_cnt) {
    int i = blockIdx.x * blockDim.x + threadIdx.x;
    if (i < NN) {
        cursor[i] = i * CAP;
        degx[i] = 0.f;
    }
    if (i == 0) *ovf_cnt = 0;
}

// ---------------- build: scatter edges into fixed-cap buckets ----------------

__global__ void build_kernel(const int* __restrict__ row, const int* __restrict__ col,
                             const float* __restrict__ ew, int* __restrict__ cursor,
                             ulong64* __restrict__ sedge, float* __restrict__ degx,
                             int* __restrict__ ovf_cnt, int4* __restrict__ ovf) {
    int e = blockIdx.x * blockDim.x + threadIdx.x;
    if (e >= NE) return;
    int r = row[e];
    int c = col[e];
    float w = ew[e];
    int pos = atomicAdd(&cursor[c], 1);
    if (pos < c * CAP + CAP) {
        sedge[pos] = ((ulong64)__float_as_uint(w) << 32) | (uint32)r;
    } else {
        int o = atomicAdd(ovf_cnt, 1);
        if (o < OVF_CAP) {
            ovf[o] = make_int4(r, c, __float_as_int(w), 0);
            atomicAdd(&degx[c], w);
        }
    }
}

// ---------------- weighted degree from buckets -> dis (wave per node) ----------------

__global__ __launch_bounds__(256) void degdis_kernel(const int* __restrict__ cursor,
                                                     const ulong64* __restrict__ sedge,
                                                     const float* __restrict__ degx,
                                                     float* __restrict__ dis) {
    int lane = threadIdx.x & 63;
    int n = blockIdx.x * 4 + (threadIdx.x >> 6);
    if (n >= NN) return;
    int cnt = min(cursor[n] - n * CAP, CAP);
    float w = 0.f;
    if (lane < cnt) w = __uint_as_float((uint32)(sedge[(size_t)n * CAP + lane] >> 32));
#pragma unroll
    for (int off = 32; off > 0; off >>= 1) w += __shfl_xor(w, off);
    if (lane == 0) dis[n] = rsqrtf(w + degx[n] + 1.0f);
}

// ---------------- repack (row, w) -> (row, norm) in place ----------------

__global__ __launch_bounds__(256) void snorm_kernel(const int* __restrict__ cursor,
                                                    ulong64* __restrict__ sedge,
                                                    const float* __restrict__ dis) {
    int lane = threadIdx.x & 63;
    int n = blockIdx.x * 4 + (threadIdx.x >> 6);
    if (n >= NN) return;
    int cnt = min(cursor[n] - n * CAP, CAP);
    float dn = dis[n];
    if (lane < cnt) {
        size_t s = (size_t)n * CAP + lane;
        ulong64 pk = sedge[s];
        int r = (int)(uint32)pk;
        float w = __uint_as_float((uint32)(pk >> 32));
        float nrm = dn * w * dis[r];
        sedge[s] = ((ulong64)__float_as_uint(nrm) << 32) | (uint32)r;
    }
}

// ---------------- GEMM: out[N x 64] = act(A[N x K]) @ W[K x 64] ----------------

template <int K, bool LEAKY>
__global__ __launch_bounds__(256) void gemm_kernel(const float* __restrict__ A,
                                                   const float* __restrict__ W,
                                                   float* __restrict__ out) {
    __shared__ float Xs[64][68];  // [k][node], padded
    __shared__ float Ws[64][64];  // [k][j]
    const int nb = blockIdx.x * 64;
    const int jt = threadIdx.x & 15;
    const int nt = threadIdx.x >> 4;

    float acc[4][4];
#pragma unroll
    for (int a = 0; a < 4; a++)
#pragma unroll
        for (int b = 0; b < 4; b++) acc[a][b] = 0.f;

    for (int k0 = 0; k0 < K; k0 += 64) {
#pragma unroll
        for (int l = 0; l < 4; l++) {
            int idx = threadIdx.x + l * 256;
            int r = idx >> 4;
            int c = (idx & 15) * 4;
            int gr = nb + r;
            float4 v = make_float4(0.f, 0.f, 0.f, 0.f);
            if (gr < NN) v = *(const float4*)&A[(size_t)gr * K + k0 + c];
            if (LEAKY) {
                v.x = v.x > 0.f ? v.x : 0.01f * v.x;
                v.y = v.y > 0.f ? v.y : 0.01f * v.y;
                v.z = v.z > 0.f ? v.z : 0.01f * v.z;
                v.w = v.w > 0.f ? v.w : 0.01f * v.w;
            }
            Xs[c][r] = v.x; Xs[c + 1][r] = v.y; Xs[c + 2][r] = v.z; Xs[c + 3][r] = v.w;
        }
#pragma unroll
        for (int l = 0; l < 4; l++) {
            int idx = threadIdx.x + l * 256;
            int r = idx >> 4;
            int c = (idx & 15) * 4;
            *(float4*)&Ws[r][c] = *(const float4*)&W[(size_t)(k0 + r) * HID + c];
        }
        __syncthreads();

#pragma unroll 8
        for (int k = 0; k < 64; k++) {
            float4 xv = *(const float4*)&Xs[k][nt * 4];
            float4 wv = *(const float4*)&Ws[k][jt * 4];
            float xa[4] = {xv.x, xv.y, xv.z, xv.w};
            float wa[4] = {wv.x, wv.y, wv.z, wv.w};
#pragma unroll
            for (int a = 0; a < 4; a++)
#pragma unroll
                for (int b = 0; b < 4; b++) acc[a][b] = fmaf(xa[a], wa[b], acc[a][b]);
        }
        __syncthreads();
    }

#pragma unroll
    for (int a = 0; a < 4; a++) {
        int node = nb + nt * 4 + a;
        if (node < NN) {
            float4 o = make_float4(acc[a][0], acc[a][1], acc[a][2], acc[a][3]);
            *(float4*)&out[(size_t)node * HID + jt * 4] = o;
        }
    }
}

// ---------------- bucket aggregate: wave per node, lane = feature ----------------

__global__ __launch_bounds__(256) void aggregate_kernel(const int* __restrict__ cursor,
                                                        const ulong64* __restrict__ sedge,
                                                        const float* __restrict__ dis,
                                                        const float* __restrict__ h,
                                                        const float* __restrict__ bias,
                                                        float* __restrict__ out) {
    int lane = threadIdx.x & 63;
    int n = blockIdx.x * 4 + (threadIdx.x >> 6);
    if (n >= NN) return;
    int cnt = min(cursor[n] - n * CAP, CAP);
    // lane-parallel coalesced slot load, then shuffle-broadcast
    ulong64 pk = 0;
    if (lane < cnt) pk = sedge[(size_t)n * CAP + lane];
    int r_l = (int)(uint32)pk;
    float w_l = __uint_as_float((uint32)(pk >> 32));

    float d = dis[n];
    float acc = bias[lane] + d * d * h[(size_t)n * HID + lane];
    int j = 0;
    for (; j + 3 < cnt; j += 4) {
        int r0 = __shfl(r_l, j), r1 = __shfl(r_l, j + 1);
        int r2 = __shfl(r_l, j + 2), r3 = __shfl(r_l, j + 3);
        float w0 = __shfl(w_l, j), w1 = __shfl(w_l, j + 1);
        float w2 = __shfl(w_l, j + 2), w3 = __shfl(w_l, j + 3);
        float v0 = h[(size_t)r0 * HID + lane];
        float v1 = h[(size_t)r1 * HID + lane];
        float v2 = h[(size_t)r2 * HID + lane];
        float v3 = h[(size_t)r3 * HID + lane];
        acc = fmaf(w0, v0, acc);
        acc = fmaf(w1, v1, acc);
        acc = fmaf(w2, v2, acc);
        acc = fmaf(w3, v3, acc);
    }
    for (; j < cnt; j++) {
        int rj = __shfl(r_l, j);
        float wj = __shfl(w_l, j);
        acc = fmaf(wj, h[(size_t)rj * HID + lane], acc);
    }
    out[(size_t)n * HID + lane] = acc;
}

// ---------------- overflow edges: rare, fp32 atomics (after aggregate) ----------------

__global__ __launch_bounds__(256) void ovf_kernel(const int* __restrict__ ovf_cnt,
                                                  const int4* __restrict__ ovf,
                                                  const float* __restrict__ dis,
                                                  const float* __restrict__ h,
                                                  float* __restrict__ out) {
    int lane = threadIdx.x & 63;
    int wid = blockIdx.x * 4 + (threadIdx.x >> 6);
    int nw = gridDim.x * 4;
    int cnt = min(*ovf_cnt, OVF_CAP);
    for (int i = wid; i < cnt; i += nw) {
        int4 t = ovf[i];
        float w = __int_as_float(t.z);
        float nrm = dis[t.x] * w * dis[t.y];
        atomicAdd(&out[(size_t)t.y * HID + lane], nrm * h[(size_t)t.x * HID + lane]);
    }
}

// ---------------- MLP head + softmax (wave per node) ----------------

__global__ __launch_bounds__(256) void mlp_kernel(const float* __restrict__ agg,
                                                  const float* __restrict__ Wm1,
                                                  const float* __restrict__ bm1,
                                                  const float* __restrict__ Wm2,
                                                  const float* __restrict__ bm2,
                                                  float* __restrict__ out) {
    __shared__ float W1s[64 * 64];
    __shared__ float W2s[128];
    for (int idx = threadIdx.x * 4; idx < 64 * 64; idx += 256 * 4)
        *(float4*)&W1s[idx] = *(const float4*)&Wm1[idx];
    if (threadIdx.x < 128) W2s[threadIdx.x] = Wm2[threadIdx.x];
    __syncthreads();

    int lane = threadIdx.x & 63;
    int wid = threadIdx.x >> 6;
    int gw = blockIdx.x * 4 + wid;
    int nw = gridDim.x * 4;
    float b1v = bm1[lane];
    float b20 = bm2[0], b21 = bm2[1];
    float w20 = W2s[lane * 2], w21 = W2s[lane * 2 + 1];

    for (int n = gw; n < NN; n += nw) {
        float hv = agg[(size_t)n * HID + lane];
        float acc = b1v;
#pragma unroll
        for (int k = 0; k < 64; k++) acc = fmaf(__shfl(hv, k), W1s[k * 64 + lane], acc);
        float u = acc > 0.f ? acc : (expf(acc) - 1.f);  // ELU
        float p0 = u * w20;
        float p1 = u * w21;
#pragma unroll
        for (int off = 32; off > 0; off >>= 1) {
            p0 += __shfl_xor(p0, off);
            p1 += __shfl_xor(p1, off);
        }
        if (lane == 0) {
            float l0 = p0 + b20, l1 = p1 + b21;
            float m = fmaxf(l0, l1);
            float e0 = expf(l0 - m), e1 = expf(l1 - m);
            float inv = 1.f / (e0 + e1);
            out[(size_t)n * 2] = e0 * inv;
            out[(size_t)n * 2 + 1] = e1 * inv;
        }
    }
}

// ---------------- launch ----------------

extern "C" void kernel_launch(void* const* d_in, const int* in_sizes, int n_in,
                              void* d_out, int out_size, void* d_ws, size_t ws_size,
                              hipStream_t stream) {
    const float* X   = (const float*)d_in[0];
    const int*   ei  = (const int*)d_in[1];
    const float* ew  = (const float*)d_in[2];
    const float* W1  = (const float*)d_in[3];
    const float* b1  = (const float*)d_in[4];
    const float* W2  = (const float*)d_in[5];
    const float* b2  = (const float*)d_in[6];
    const float* Wm1 = (const float*)d_in[7];
    const float* bm1 = (const float*)d_in[8];
    const float* Wm2 = (const float*)d_in[9];
    const float* bm2 = (const float*)d_in[10];
    const int* row = ei;
    const int* col = ei + NE;
    float* out = (float*)d_out;

    const size_t MB = 1024 * 1024;
    char* ws = (char*)d_ws;
    float*   dis     = (float*)  (ws + 0 * MB);   // NN floats (0.4 MB)
    int*     cursor  = (int*)    (ws + 1 * MB);   // NN ints   (0.4 MB)
    float*   degx    = (float*)  (ws + 2 * MB);   // NN floats (0.4 MB)
    int*     ovf_cnt = (int*)    (ws + 3 * MB);   // 1 int
    int4*    ovf     = (int4*)   (ws + 4 * MB);   // OVF_CAP * 16 B (1 MB)
    ulong64* sedge   = (ulong64*)(ws + 5 * MB);   // NN*CAP*8 = 38.4 MB
    float*   h1      = (float*)  (ws + 44 * MB);  // NN*64 (25.6 MB)
    float*   h2      = (float*)  (ws + 70 * MB);  // NN*64 (25.6 MB) -> 95.6 MB total

    // ---- bucketed CSR build + norm ----
    init_kernel<<<(NN + 255) / 256, 256, 0, stream>>>(cursor, degx, ovf_cnt);
    build_kernel<<<(NE + 255) / 256, 256, 0, stream>>>(row, col, ew, cursor, sedge, degx,
                                                       ovf_cnt, ovf);
    degdis_kernel<<<(NN + 3) / 4, 256, 0, stream>>>(cursor, sedge, degx, dis);
    snorm_kernel<<<(NN + 3) / 4, 256, 0, stream>>>(cursor, sedge, dis);

    // ---- conv1 ----
    gemm_kernel<INF, false><<<(NN + 63) / 64, 256, 0, stream>>>(X, W1, h1);
    aggregate_kernel<<<(NN + 3) / 4, 256, 0, stream>>>(cursor, sedge, dis, h1, b1, h2);
    ovf_kernel<<<256, 256, 0, stream>>>(ovf_cnt, ovf, dis, h1, h2);

    // ---- conv2 ----
    gemm_kernel<HID, true><<<(NN + 63) / 64, 256, 0, stream>>>(h2, W2, h1);
    aggregate_kernel<<<(NN + 3) / 4, 256, 0, stream>>>(cursor, sedge, dis, h1, b2, h2);
    ovf_kernel<<<256, 256, 0, stream>>>(ovf_cnt, ovf, dis, h1, h2);

    // ---- MLP head + softmax ----
    mlp_kernel<<<2048, 256, 0, stream>>>(h2, Wm1, bm1, Wm2, bm2, out);
}

// Round 5
// 790.093 us; speedup vs baseline: 2.4190x; 1.1078x over previous
//
#include <hip/hip_runtime.h>
#include <math.h>

#define NN 100000
#define NE 3200000
#define INF 384
#define HID 64
#define CAP 48
#define OVF_CAP 65536
#define NBIN 98             // bin = col >> 10 (1024 nodes per bin)
#define NREP 8              // replicas per bin (blockIdx & 7 ~ XCD id)
#define NCTR (NBIN * NREP)  // 784

typedef unsigned long long ulong64;
typedef unsigned int uint32;

// ---------------- init: degx, ovf_cnt, bin counters ----------------

__global__ void init_kernel(float* __restrict__ degx, int* __restrict__ ovf_cnt,
                            int* __restrict__ bincnt) {
    int i = blockIdx.x * blockDim.x + threadIdx.x;
    if (i < NN) degx[i] = 0.f;
    if (i < NCTR) bincnt[i] = 0;
    if (i == 0) *ovf_cnt = 0;
}

// ---------------- pass 1: per-bin histogram (LDS-aggregated) ----------------
// MUST use the exact same edge->block tiling as binscatter_kernel so the
// per-replica counts match the per-replica allocations (round-4 bug).

__global__ __launch_bounds__(256) void binhist_kernel(const int* __restrict__ col,
                                                      int* __restrict__ bincnt) {
    __shared__ int h[NBIN];
    if (threadIdx.x < NBIN) h[threadIdx.x] = 0;
    __syncthreads();
    int rep = blockIdx.x & (NREP - 1);
    for (int base = blockIdx.x * 1024; base < NE; base += gridDim.x * 1024) {
#pragma unroll
        for (int i = 0; i < 4; i++) {
            int e = base + i * 256 + threadIdx.x;
            if (e < NE) atomicAdd(&h[col[e] >> 10], 1);
        }
    }
    __syncthreads();
    if (threadIdx.x < NBIN && h[threadIdx.x] > 0)
        atomicAdd(&bincnt[threadIdx.x * NREP + rep], h[threadIdx.x]);
}

// ---------------- pass 2: exclusive scan of 784 replica counters ----------------

__global__ __launch_bounds__(256) void binscan_kernel(const int* __restrict__ bincnt,
                                                      int* __restrict__ binbase,
                                                      int* __restrict__ bincur) {
    __shared__ int tot[256];
    int t = threadIdx.x;
    int v[4];
    int s = 0;
#pragma unroll
    for (int i = 0; i < 4; i++) {
        int idx = t * 4 + i;
        v[i] = (idx < NCTR) ? bincnt[idx] : 0;
        s += v[i];
    }
    tot[t] = s;
    __syncthreads();
    for (int off = 1; off < 256; off <<= 1) {
        int x = (t >= off) ? tot[t - off] : 0;
        __syncthreads();
        tot[t] += x;
        __syncthreads();
    }
    int run = tot[t] - s;
#pragma unroll
    for (int i = 0; i < 4; i++) {
        int idx = t * 4 + i;
        if (idx < NCTR) { binbase[idx] = run; bincur[idx] = run; }
        run += v[i];
    }
    if (t == 255) binbase[NCTR] = NE;
}

// ---------------- pass 3: scatter edges into bin replicas ----------------
// payload: [w:32][col_local:10][row:17]

__global__ __launch_bounds__(256) void binscatter_kernel(const int* __restrict__ row,
                                                         const int* __restrict__ col,
                                                         const float* __restrict__ ew,
                                                         int* __restrict__ bincur,
                                                         ulong64* __restrict__ ebin) {
    __shared__ int lhist[NBIN];
    __shared__ int lbase[NBIN];
    int tid = threadIdx.x;
    int rep = blockIdx.x & (NREP - 1);
    for (int base = blockIdx.x * 1024; base < NE; base += gridDim.x * 1024) {
        if (tid < NBIN) lhist[tid] = 0;
        __syncthreads();
        int rr[4], bb[4], rk[4];
        float w[4];
#pragma unroll
        for (int i = 0; i < 4; i++) {
            int e = base + i * 256 + tid;
            bb[i] = -1;
            if (e < NE) {
                int r = row[e];
                int c = col[e];
                w[i] = ew[e];
                bb[i] = c >> 10;
                rk[i] = atomicAdd(&lhist[bb[i]], 1);
                rr[i] = r | ((c & 1023) << 17);
            }
        }
        __syncthreads();
        if (tid < NBIN && lhist[tid] > 0)
            lbase[tid] = atomicAdd(&bincur[tid * NREP + rep], lhist[tid]);
        __syncthreads();
#pragma unroll
        for (int i = 0; i < 4; i++)
            if (bb[i] >= 0) {
                int pos = lbase[bb[i]] + rk[i];
                ebin[pos] = ((ulong64)__float_as_uint(w[i]) << 32) | (uint32)rr[i];
            }
        __syncthreads();
    }
}

// ---------------- pass 4: build per-node buckets, LDS cursors ----------------

__global__ __launch_bounds__(1024) void bucket_kernel(const int* __restrict__ binbase,
                                                      const ulong64* __restrict__ ebin,
                                                      ulong64* __restrict__ sedge,
                                                      int* __restrict__ cnt,
                                                      float* __restrict__ degx,
                                                      int* __restrict__ ovf_cnt,
                                                      int4* __restrict__ ovf) {
    __shared__ int cur[1024];
    int bin = blockIdx.x;
    int node0 = bin << 10;
    cur[threadIdx.x] = 0;
    __syncthreads();
    int start = binbase[bin * NREP];
    int end = binbase[(bin + 1) * NREP];
    for (int i = start + threadIdx.x; i < end; i += 1024) {
        ulong64 pk = ebin[i];
        int r = (int)(pk & 0x1FFFF);
        int lc = (int)((pk >> 17) & 1023);
        uint32 wb = (uint32)(pk >> 32);
        int rank = atomicAdd(&cur[lc], 1);  // LDS atomic
        int node = node0 + lc;
        if (rank < CAP) {
            sedge[(size_t)node * CAP + rank] = ((ulong64)wb << 32) | (uint32)r;
        } else {
            int o = atomicAdd(ovf_cnt, 1);
            if (o < OVF_CAP) {
                ovf[o] = make_int4(r, node, (int)wb, 0);
                atomicAdd(&degx[node], __uint_as_float(wb));
            }
        }
    }
    __syncthreads();
    int node = node0 + threadIdx.x;
    if (node < NN) cnt[node] = min(cur[threadIdx.x], CAP);
}

// ---------------- weighted degree -> dis (wave per node) ----------------

__global__ __launch_bounds__(256) void degdis_kernel(const int* __restrict__ cnt,
                                                     const ulong64* __restrict__ sedge,
                                                     const float* __restrict__ degx,
                                                     float* __restrict__ dis) {
    int lane = threadIdx.x & 63;
    int n = blockIdx.x * 4 + (threadIdx.x >> 6);
    if (n >= NN) return;
    int c = cnt[n];
    float w = 0.f;
    if (lane < c) w = __uint_as_float((uint32)(sedge[(size_t)n * CAP + lane] >> 32));
#pragma unroll
    for (int off = 32; off > 0; off >>= 1) w += __shfl_xor(w, off);
    if (lane == 0) dis[n] = rsqrtf(w + degx[n] + 1.0f);
}

// ---------------- repack (row, w) -> (row, norm) in place ----------------

__global__ __launch_bounds__(256) void snorm_kernel(const int* __restrict__ cnt,
                                                    ulong64* __restrict__ sedge,
                                                    const float* __restrict__ dis) {
    int lane = threadIdx.x & 63;
    int n = blockIdx.x * 4 + (threadIdx.x >> 6);
    if (n >= NN) return;
    int c = cnt[n];
    float dn = dis[n];
    if (lane < c) {
        size_t s = (size_t)n * CAP + lane;
        ulong64 pk = sedge[s];
        int r = (int)(uint32)pk;
        float w = __uint_as_float((uint32)(pk >> 32));
        float nrm = dn * w * dis[r];
        sedge[s] = ((ulong64)__float_as_uint(nrm) << 32) | (uint32)r;
    }
}

// ---------------- GEMM: out[N x 64] = act(A[N x K]) @ W[K x 64] ----------------

template <int K, bool LEAKY>
__global__ __launch_bounds__(256) void gemm_kernel(const float* __restrict__ A,
                                                   const float* __restrict__ W,
                                                   float* __restrict__ out) {
    __shared__ float Xs[64][68];  // [k][node], padded
    __shared__ float Ws[64][64];  // [k][j]
    const int nb = blockIdx.x * 64;
    const int jt = threadIdx.x & 15;
    const int nt = threadIdx.x >> 4;

    float acc[4][4];
#pragma unroll
    for (int a = 0; a < 4; a++)
#pragma unroll
        for (int b = 0; b < 4; b++) acc[a][b] = 0.f;

    for (int k0 = 0; k0 < K; k0 += 64) {
#pragma unroll
        for (int l = 0; l < 4; l++) {
            int idx = threadIdx.x + l * 256;
            int r = idx >> 4;
            int c = (idx & 15) * 4;
            int gr = nb + r;
            float4 v = make_float4(0.f, 0.f, 0.f, 0.f);
            if (gr < NN) v = *(const float4*)&A[(size_t)gr * K + k0 + c];
            if (LEAKY) {
                v.x = v.x > 0.f ? v.x : 0.01f * v.x;
                v.y = v.y > 0.f ? v.y : 0.01f * v.y;
                v.z = v.z > 0.f ? v.z : 0.01f * v.z;
                v.w = v.w > 0.f ? v.w : 0.01f * v.w;
            }
            Xs[c][r] = v.x; Xs[c + 1][r] = v.y; Xs[c + 2][r] = v.z; Xs[c + 3][r] = v.w;
        }
#pragma unroll
        for (int l = 0; l < 4; l++) {
            int idx = threadIdx.x + l * 256;
            int r = idx >> 4;
            int c = (idx & 15) * 4;
            *(float4*)&Ws[r][c] = *(const float4*)&W[(size_t)(k0 + r) * HID + c];
        }
        __syncthreads();

#pragma unroll 8
        for (int k = 0; k < 64; k++) {
            float4 xv = *(const float4*)&Xs[k][nt * 4];
            float4 wv = *(const float4*)&Ws[k][jt * 4];
            float xa[4] = {xv.x, xv.y, xv.z, xv.w};
            float wa[4] = {wv.x, wv.y, wv.z, wv.w};
#pragma unroll
            for (int a = 0; a < 4; a++)
#pragma unroll
                for (int b = 0; b < 4; b++) acc[a][b] = fmaf(xa[a], wa[b], acc[a][b]);
        }
        __syncthreads();
    }

#pragma unroll
    for (int a = 0; a < 4; a++) {
        int node = nb + nt * 4 + a;
        if (node < NN) {
            float4 o = make_float4(acc[a][0], acc[a][1], acc[a][2], acc[a][3]);
            *(float4*)&out[(size_t)node * HID + jt * 4] = o;
        }
    }
}

// ---------------- bucket aggregate: wave per node, lane = feature ----------------

__global__ __launch_bounds__(256) void aggregate_kernel(const int* __restrict__ cnt,
                                                        const ulong64* __restrict__ sedge,
                                                        const float* __restrict__ dis,
                                                        const float* __restrict__ h,
                                                        const float* __restrict__ bias,
                                                        float* __restrict__ out) {
    int lane = threadIdx.x & 63;
    int n = blockIdx.x * 4 + (threadIdx.x >> 6);
    if (n >= NN) return;
    int c = cnt[n];
    ulong64 pk = 0;
    if (lane < c) pk = sedge[(size_t)n * CAP + lane];
    int r_l = (int)(uint32)pk;
    float w_l = __uint_as_float((uint32)(pk >> 32));

    float d = dis[n];
    float acc = bias[lane] + d * d * h[(size_t)n * HID + lane];
    int j = 0;
    for (; j + 3 < c; j += 4) {
        int r0 = __shfl(r_l, j), r1 = __shfl(r_l, j + 1);
        int r2 = __shfl(r_l, j + 2), r3 = __shfl(r_l, j + 3);
        float w0 = __shfl(w_l, j), w1 = __shfl(w_l, j + 1);
        float w2 = __shfl(w_l, j + 2), w3 = __shfl(w_l, j + 3);
        float v0 = h[(size_t)r0 * HID + lane];
        float v1 = h[(size_t)r1 * HID + lane];
        float v2 = h[(size_t)r2 * HID + lane];
        float v3 = h[(size_t)r3 * HID + lane];
        acc = fmaf(w0, v0, acc);
        acc = fmaf(w1, v1, acc);
        acc = fmaf(w2, v2, acc);
        acc = fmaf(w3, v3, acc);
    }
    for (; j < c; j++) {
        int rj = __shfl(r_l, j);
        float wj = __shfl(w_l, j);
        acc = fmaf(wj, h[(size_t)rj * HID + lane], acc);
    }
    out[(size_t)n * HID + lane] = acc;
}

// ---------------- overflow edges: rare, fp32 atomics ----------------

__global__ __launch_bounds__(256) void ovf_kernel(const int* __restrict__ ovf_cnt,
                                                  const int4* __restrict__ ovf,
                                                  const float* __restrict__ dis,
                                                  const float* __restrict__ h,
                                                  float* __restrict__ out) {
    int lane = threadIdx.x & 63;
    int wid = blockIdx.x * 4 + (threadIdx.x >> 6);
    int nw = gridDim.x * 4;
    int c = min(*ovf_cnt, OVF_CAP);
    for (int i = wid; i < c; i += nw) {
        int4 t = ovf[i];
        float w = __int_as_float(t.z);
        float nrm = dis[t.x] * w * dis[t.y];
        atomicAdd(&out[(size_t)t.y * HID + lane], nrm * h[(size_t)t.x * HID + lane]);
    }
}

// ---------------- MLP head + softmax (wave per node) ----------------

__global__ __launch_bounds__(256) void mlp_kernel(const float* __restrict__ agg,
                                                  const float* __restrict__ Wm1,
                                                  const float* __restrict__ bm1,
                                                  const float* __restrict__ Wm2,
                                                  const float* __restrict__ bm2,
                                                  float* __restrict__ out) {
    __shared__ float W1s[64 * 64];
    __shared__ float W2s[128];
    for (int idx = threadIdx.x * 4; idx < 64 * 64; idx += 256 * 4)
        *(float4*)&W1s[idx] = *(const float4*)&Wm1[idx];
    if (threadIdx.x < 128) W2s[threadIdx.x] = Wm2[threadIdx.x];
    __syncthreads();

    int lane = threadIdx.x & 63;
    int wid = threadIdx.x >> 6;
    int gw = blockIdx.x * 4 + wid;
    int nw = gridDim.x * 4;
    float b1v = bm1[lane];
    float b20 = bm2[0], b21 = bm2[1];
    float w20 = W2s[lane * 2], w21 = W2s[lane * 2 + 1];

    for (int n = gw; n < NN; n += nw) {
        float hv = agg[(size_t)n * HID + lane];
        float acc = b1v;
#pragma unroll
        for (int k = 0; k < 64; k++) acc = fmaf(__shfl(hv, k), W1s[k * 64 + lane], acc);
        float u = acc > 0.f ? acc : (expf(acc) - 1.f);  // ELU
        float p0 = u * w20;
        float p1 = u * w21;
#pragma unroll
        for (int off = 32; off > 0; off >>= 1) {
            p0 += __shfl_xor(p0, off);
            p1 += __shfl_xor(p1, off);
        }
        if (lane == 0) {
            float l0 = p0 + b20, l1 = p1 + b21;
            float m = fmaxf(l0, l1);
            float e0 = expf(l0 - m), e1 = expf(l1 - m);
            float inv = 1.f / (e0 + e1);
            out[(size_t)n * 2] = e0 * inv;
            out[(size_t)n * 2 + 1] = e1 * inv;
        }
    }
}

// ---------------- launch ----------------

extern "C" void kernel_launch(void* const* d_in, const int* in_sizes, int n_in,
                              void* d_out, int out_size, void* d_ws, size_t ws_size,
                              hipStream_t stream) {
    const float* X   = (const float*)d_in[0];
    const int*   ei  = (const int*)d_in[1];
    const float* ew  = (const float*)d_in[2];
    const float* W1  = (const float*)d_in[3];
    const float* b1  = (const float*)d_in[4];
    const float* W2  = (const float*)d_in[5];
    const float* b2  = (const float*)d_in[6];
    const float* Wm1 = (const float*)d_in[7];
    const float* bm1 = (const float*)d_in[8];
    const float* Wm2 = (const float*)d_in[9];
    const float* bm2 = (const float*)d_in[10];
    const int* row = ei;
    const int* col = ei + NE;
    float* out = (float*)d_out;

    const size_t MB = 1024 * 1024;
    char* ws = (char*)d_ws;
    float*   dis     = (float*)  (ws + 0 * MB);           // NN floats (0.4 MB)
    int*     cnt     = (int*)    (ws + 1 * MB);           // NN ints   (0.4 MB)
    float*   degx    = (float*)  (ws + 2 * MB);           // NN floats (0.4 MB)
    int*     ovf_cnt = (int*)    (ws + 3 * MB);           // 1 int
    int*     binbase = (int*)    (ws + 3 * MB + 4096);    // NCTR+1 ints
    int*     bincur  = (int*)    (ws + 3 * MB + 16384);   // NCTR ints
    int*     bincnt  = (int*)    (ws + 3 * MB + 32768);   // NCTR ints
    int4*    ovf     = (int4*)   (ws + 4 * MB);           // OVF_CAP*16 (1 MB)
    ulong64* ebin    = (ulong64*)(ws + 5 * MB);           // NE*8 = 25.6 MB
    float*   h2      = (float*)  (ws + 5 * MB);           // overlays ebin (consumed first)
    ulong64* sedge   = (ulong64*)(ws + 31 * MB);          // NN*CAP*8 = 38.4 MB
    float*   h1      = (float*)  (ws + 70 * MB);          // NN*64 (25.6 MB) -> 95.6 MB

    // ---- binned bucket build + norm ----
    init_kernel<<<(NN + 255) / 256, 256, 0, stream>>>(degx, ovf_cnt, bincnt);
    binhist_kernel<<<1024, 256, 0, stream>>>(col, bincnt);
    binscan_kernel<<<1, 256, 0, stream>>>(bincnt, binbase, bincur);
    binscatter_kernel<<<1024, 256, 0, stream>>>(row, col, ew, bincur, ebin);
    bucket_kernel<<<NBIN, 1024, 0, stream>>>(binbase, ebin, sedge, cnt, degx, ovf_cnt, ovf);
    degdis_kernel<<<(NN + 3) / 4, 256, 0, stream>>>(cnt, sedge, degx, dis);
    snorm_kernel<<<(NN + 3) / 4, 256, 0, stream>>>(cnt, sedge, dis);

    // ---- conv1 ----
    gemm_kernel<INF, false><<<(NN + 63) / 64, 256, 0, stream>>>(X, W1, h1);
    aggregate_kernel<<<(NN + 3) / 4, 256, 0, stream>>>(cnt, sedge, dis, h1, b1, h2);
    ovf_kernel<<<256, 256, 0, stream>>>(ovf_cnt, ovf, dis, h1, h2);

    // ---- conv2 ----
    gemm_kernel<HID, true><<<(NN + 63) / 64, 256, 0, stream>>>(h2, W2, h1);
    aggregate_kernel<<<(NN + 3) / 4, 256, 0, stream>>>(cnt, sedge, dis, h1, b2, h2);
    ovf_kernel<<<256, 256, 0, stream>>>(ovf_cnt, ovf, dis, h1, h2);

    // ---- MLP head + softmax ----
    mlp_kernel<<<2048, 256, 0, stream>>>(h2, Wm1, bm1, Wm2, bm2, out);
}